// Round 1
// baseline (2657.758 us; speedup 1.0000x reference)
//
#include <hip/hip_runtime.h>
#include <hip/hip_bf16.h>
#include <math.h>

// Problem constants
constexpr int Bz = 4, Cz = 128, Dz = 16, Hz = 56, Wz = 56;
constexpr int Kz = 32, MIDz = 32;
constexpr int HWz = Hz * Wz;           // 3136
constexpr int NCHUNK = (HWz + 255) / 256; // 13

// Workspace layout (float offsets)
constexpr size_t OFF_POOLED   = 0;                       // 8192
constexpr size_t OFF_DENOM    = 8192;                    // 8192
constexpr size_t OFF_CW       = 16384;                   // 8192
constexpr size_t OFF_IMP      = 24576;                   // 8192
constexpr size_t OFF_S        = 32768;                   // 200704
constexpr size_t OFF_SEL      = 233472;                  // 2048 ints
constexpr size_t OFF_INV      = 235520;                  // 8192 ints
constexpr size_t OFF_SELECTED = 243712;                  // 6422528

// ---------------- Kernel 1: per-(b,c,d) mean and L2 norm ----------------
__global__ __launch_bounds__(256) void k_stats(const float* __restrict__ x,
                                               float* __restrict__ pooled,
                                               float* __restrict__ denom) {
    int bcd = blockIdx.x;
    const float* p = x + (size_t)bcd * HWz;
    float s = 0.f, ss = 0.f;
    for (int i = threadIdx.x; i < HWz; i += 256) {
        float v = p[i];
        s += v; ss += v * v;
    }
    __shared__ float r1[256], r2[256];
    r1[threadIdx.x] = s; r2[threadIdx.x] = ss;
    __syncthreads();
    for (int o = 128; o > 0; o >>= 1) {
        if (threadIdx.x < o) {
            r1[threadIdx.x] += r1[threadIdx.x + o];
            r2[threadIdx.x] += r2[threadIdx.x + o];
        }
        __syncthreads();
    }
    if (threadIdx.x == 0) {
        pooled[bcd] = r1[0] / (float)HWz;
        denom[bcd]  = fmaxf(sqrtf(r2[0]), 1e-12f);
    }
}

// ---------------- Kernel 2: channel attention MLP ----------------
__global__ __launch_bounds__(128) void k_attn(const float* __restrict__ pooled,
                                              const float* __restrict__ w1,
                                              const float* __restrict__ b1,
                                              const float* __restrict__ w2,
                                              const float* __restrict__ b2,
                                              float* __restrict__ cw) {
    int bd = blockIdx.x;
    int b = bd / Dz, d = bd % Dz;
    int c = threadIdx.x;
    __shared__ float ps[Cz], hs[MIDz];
    ps[c] = pooled[(size_t)(b * Cz + c) * Dz + d];
    __syncthreads();
    if (c < MIDz) {
        float a = b1[c];
        for (int j = 0; j < Cz; j++) a += w1[c * Cz + j] * ps[j];
        hs[c] = fmaxf(a, 0.f);
    }
    __syncthreads();
    float a = b2[c];
    for (int m = 0; m < MIDz; m++) a += w2[c * MIDz + m] * hs[m];
    cw[(size_t)(b * Cz + c) * Dz + d] = 1.f / (1.f + expf(-a));
}

// ---------------- Kernel 3: s[b,d,n] = sum_c x/denom ----------------
__global__ __launch_bounds__(256) void k_s(const float* __restrict__ x,
                                           const float* __restrict__ denom,
                                           float* __restrict__ s) {
    int blk = blockIdx.x;
    int chunk = blk % NCHUNK;
    int bd = blk / NCHUNK;
    int b = bd / Dz, d = bd % Dz;
    __shared__ float rd[Cz];
    if (threadIdx.x < Cz)
        rd[threadIdx.x] = 1.f / denom[(size_t)(b * Cz + threadIdx.x) * Dz + d];
    __syncthreads();
    int n = chunk * 256 + threadIdx.x;
    if (n >= HWz) return;
    float acc = 0.f;
    const float* xp = x + ((size_t)(b * Cz) * Dz + d) * HWz + n;
    for (int c = 0; c < Cz; c++)
        acc += xp[(size_t)c * Dz * HWz] * rd[c];
    s[(size_t)bd * HWz + n] = acc;
}

// ---------------- Kernel 4: sim dot + importance ----------------
__global__ __launch_bounds__(256) void k_imp(const float* __restrict__ x,
                                             const float* __restrict__ s,
                                             const float* __restrict__ denom,
                                             const float* __restrict__ cw,
                                             const float* __restrict__ alpha,
                                             float* __restrict__ imp) {
    int bcd = blockIdx.x;
    int d = bcd % Dz;
    int b = bcd / (Cz * Dz);
    const float* xp = x + (size_t)bcd * HWz;
    const float* sp = s + ((size_t)(b * Dz) + d) * HWz;
    float acc = 0.f;
    for (int i = threadIdx.x; i < HWz; i += 256) acc += xp[i] * sp[i];
    __shared__ float r[256];
    r[threadIdx.x] = acc;
    __syncthreads();
    for (int o = 128; o > 0; o >>= 1) {
        if (threadIdx.x < o) r[threadIdx.x] += r[threadIdx.x + o];
        __syncthreads();
    }
    if (threadIdx.x == 0) {
        float sim = r[0] / (denom[bcd] * (float)Cz);
        float al = alpha[0];
        imp[bcd] = al * (1.f - sim) + (1.f - al) * cw[bcd];
    }
}

// ---------------- Kernel 5: stable top-K (descending, lower index first) ----------------
__global__ __launch_bounds__(128) void k_topk(const float* __restrict__ imp,
                                              int* __restrict__ sel,
                                              int* __restrict__ inv) {
    int bd = blockIdx.x;
    int b = bd / Dz, d = bd % Dz;
    int c = threadIdx.x;
    __shared__ float v[Cz];
    v[c] = imp[(size_t)(b * Cz + c) * Dz + d];
    __syncthreads();
    float mv = v[c];
    int rank = 0;
    for (int j = 0; j < Cz; j++) {
        float u = v[j];
        rank += (u > mv) || (u == mv && j < c);
    }
    inv[(size_t)bd * Cz + c] = (rank < Kz) ? rank : -1;
    if (rank < Kz) sel[(size_t)bd * Kz + rank] = c;
}

// ---------------- Kernel 6: gathered 3x3x3 conv over selected channels ----------------
__global__ __launch_bounds__(256) void k_pconv(const float* __restrict__ x,
                                               const float* __restrict__ wp,
                                               const int* __restrict__ sel,
                                               float* __restrict__ selected) {
    int blk = blockIdx.x;
    int chunk = blk % NCHUNK;
    int rest = blk / NCHUNK;
    int d = rest % Dz; rest /= Dz;
    int k = rest % Kz;
    int b = rest / Kz;

    __shared__ float wk[Kz * 27];
    __shared__ int s3[3][Kz];
    for (int i = threadIdx.x; i < Kz * 27; i += 256) wk[i] = wp[(size_t)k * Kz * 27 + i];
    if (threadIdx.x < 3 * Kz) {
        int dz = threadIdx.x / Kz, j = threadIdx.x % Kz;
        int dd = d + dz - 1;
        s3[dz][j] = (dd >= 0 && dd < Dz) ? sel[(size_t)(b * Dz + dd) * Kz + j] : 0;
    }
    __syncthreads();

    int p = chunk * 256 + threadIdx.x;
    if (p >= HWz) return;
    int h = p / Wz, w = p % Wz;
    int y0 = (h == 0) ? 1 : 0, y1 = (h == Hz - 1) ? 2 : 3;
    int x0 = (w == 0) ? 1 : 0, x1 = (w == Wz - 1) ? 2 : 3;

    float acc = 0.f;
    for (int dz = 0; dz < 3; dz++) {
        int dd = d + dz - 1;
        if (dd < 0 || dd >= Dz) continue;
        for (int j = 0; j < Kz; j++) {
            int ch = s3[dz][j];
            const float* xp = x + ((size_t)(b * Cz + ch) * Dz + dd) * HWz;
            const float* wrow = wk + j * 27 + dz * 9;
            for (int dy = y0; dy < y1; dy++) {
                const float* xr = xp + (h + dy - 1) * Wz + (w - 1);
                const float* wr = wrow + dy * 3;
                #pragma unroll
                for (int dx = 0; dx < 3; dx++) {
                    if (dx >= x0 && dx < x1) acc += wr[dx] * xr[dx];
                }
            }
        }
    }
    selected[((size_t)(b * Kz + k) * Dz + d) * HWz + p] = acc;
}

// ---------------- Kernel 7: depthwise conv + BN + ReLU -> d_out ----------------
__global__ __launch_bounds__(256) void k_dw(const float* __restrict__ x,
                                            const float* __restrict__ selected,
                                            const int* __restrict__ inv,
                                            const float* __restrict__ dww,
                                            const float* __restrict__ gam,
                                            const float* __restrict__ bet,
                                            const float* __restrict__ mn,
                                            const float* __restrict__ vr,
                                            float* __restrict__ out) {
    int blk = blockIdx.x;
    int chunk = blk % NCHUNK;
    int rest = blk / NCHUNK;
    int d = rest % Dz; rest /= Dz;
    int c = rest % Cz;
    int b = rest / Cz;
    int p = chunk * 256 + threadIdx.x;
    if (p >= HWz) return;
    int h = p / Wz, w = p % Wz;
    int y0 = (h == 0) ? 1 : 0, y1 = (h == Hz - 1) ? 2 : 3;
    int x0 = (w == 0) ? 1 : 0, x1 = (w == Wz - 1) ? 2 : 3;

    float acc = 0.f;
    for (int dz = 0; dz < 3; dz++) {
        int dd = d + dz - 1;
        if (dd < 0 || dd >= Dz) continue;
        int pos = inv[(size_t)(b * Dz + dd) * Cz + c];
        const float* src = (pos >= 0)
            ? selected + ((size_t)(b * Kz + pos) * Dz + dd) * HWz
            : x + ((size_t)(b * Cz + c) * Dz + dd) * HWz;
        const float* wrow = dww + c * 27 + dz * 9;
        for (int dy = y0; dy < y1; dy++) {
            const float* xr = src + (h + dy - 1) * Wz + (w - 1);
            const float* wr = wrow + dy * 3;
            #pragma unroll
            for (int dx = 0; dx < 3; dx++) {
                if (dx >= x0 && dx < x1) acc += wr[dx] * xr[dx];
            }
        }
    }
    float sc = gam[c] * (1.f / sqrtf(vr[c] + 1e-5f));
    float v = (acc - mn[c]) * sc + bet[c];
    out[((size_t)(b * Cz + c) * Dz + d) * HWz + p] = fmaxf(v, 0.f);
}

// ---------------- Kernel 8: in-place pointwise 128x128 GEMM on d_out ----------------
__global__ __launch_bounds__(256) void k_pw(const float* __restrict__ pw,
                                            float* __restrict__ out) {
    int blk = blockIdx.x;
    int tile = blk % 49;           // 3136 / 64
    int bd = blk / 49;
    int b = bd / Dz, d = bd % Dz;
    __shared__ float yt[Cz][64];
    size_t base = ((size_t)(b * Cz) * Dz + d) * HWz + tile * 64;
    for (int i = threadIdx.x; i < Cz * 64; i += 256) {
        int c = i >> 6, p = i & 63;
        yt[c][p] = out[base + (size_t)c * Dz * HWz + p];
    }
    __syncthreads();
    int g = threadIdx.x >> 6, p = threadIdx.x & 63;
    for (int og = 0; og < 32; og++) {
        int o = g * 32 + og;
        const float* wrow = pw + (size_t)o * Cz;
        float acc = 0.f;
        #pragma unroll 8
        for (int c = 0; c < Cz; c++) acc += wrow[c] * yt[c][p];
        out[base + (size_t)o * Dz * HWz + p] = acc;
    }
}

extern "C" void kernel_launch(void* const* d_in, const int* in_sizes, int n_in,
                              void* d_out, int out_size, void* d_ws, size_t ws_size,
                              hipStream_t stream) {
    const float* x     = (const float*)d_in[0];
    const float* wp    = (const float*)d_in[1];
    const float* ca_w1 = (const float*)d_in[2];
    const float* ca_b1 = (const float*)d_in[3];
    const float* ca_w2 = (const float*)d_in[4];
    const float* ca_b2 = (const float*)d_in[5];
    const float* alpha = (const float*)d_in[6];
    const float* dw_w  = (const float*)d_in[7];
    const float* bn_g  = (const float*)d_in[8];
    const float* bn_b  = (const float*)d_in[9];
    const float* bn_m  = (const float*)d_in[10];
    const float* bn_v  = (const float*)d_in[11];
    const float* pw_w  = (const float*)d_in[12];

    float* ws = (float*)d_ws;
    float* pooled   = ws + OFF_POOLED;
    float* denom    = ws + OFF_DENOM;
    float* cw       = ws + OFF_CW;
    float* imp      = ws + OFF_IMP;
    float* s        = ws + OFF_S;
    int*   sel      = (int*)(ws + OFF_SEL);
    int*   inv      = (int*)(ws + OFF_INV);
    float* selected = ws + OFF_SELECTED;
    float* out      = (float*)d_out;

    k_stats<<<Bz * Cz * Dz, 256, 0, stream>>>(x, pooled, denom);
    k_attn<<<Bz * Dz, 128, 0, stream>>>(pooled, ca_w1, ca_b1, ca_w2, ca_b2, cw);
    k_s<<<Bz * Dz * NCHUNK, 256, 0, stream>>>(x, denom, s);
    k_imp<<<Bz * Cz * Dz, 256, 0, stream>>>(x, s, denom, cw, alpha, imp);
    k_topk<<<Bz * Dz, 128, 0, stream>>>(imp, sel, inv);
    k_pconv<<<Bz * Kz * Dz * NCHUNK, 256, 0, stream>>>(x, wp, sel, selected);
    k_dw<<<Bz * Cz * Dz * NCHUNK, 256, 0, stream>>>(x, selected, inv, dw_w,
                                                    bn_g, bn_b, bn_m, bn_v, out);
    k_pw<<<Bz * Dz * 49, 256, 0, stream>>>(pw_w, out);
}

// Round 2
// 1261.623 us; speedup vs baseline: 2.1066x; 2.1066x over previous
//
#include <hip/hip_runtime.h>
#include <hip/hip_bf16.h>
#include <math.h>

// Problem constants
constexpr int Bz = 4, Cz = 128, Dz = 16, Hz = 56, Wz = 56;
constexpr int Kz = 32, MIDz = 32;
constexpr int HWz = Hz * Wz;           // 3136
constexpr int NCHUNK = (HWz + 255) / 256; // 13

// Workspace layout (float offsets)
constexpr size_t OFF_POOLED   = 0;                       // 8192
constexpr size_t OFF_DENOM    = 8192;                    // 8192
constexpr size_t OFF_CW       = 16384;                   // 8192
constexpr size_t OFF_IMP      = 24576;                   // 8192
constexpr size_t OFF_S        = 32768;                   // 200704
constexpr size_t OFF_SEL      = 233472;                  // 2048 ints
constexpr size_t OFF_INV      = 235520;                  // 8192 ints
constexpr size_t OFF_SELECTED = 243712;                  // 6422528

// ---------------- Kernel 1: per-(b,c,d) mean and L2 norm ----------------
__global__ __launch_bounds__(256) void k_stats(const float* __restrict__ x,
                                               float* __restrict__ pooled,
                                               float* __restrict__ denom) {
    int bcd = blockIdx.x;
    const float* p = x + (size_t)bcd * HWz;
    float s = 0.f, ss = 0.f;
    for (int i = threadIdx.x; i < HWz; i += 256) {
        float v = p[i];
        s += v; ss += v * v;
    }
    __shared__ float r1[256], r2[256];
    r1[threadIdx.x] = s; r2[threadIdx.x] = ss;
    __syncthreads();
    for (int o = 128; o > 0; o >>= 1) {
        if (threadIdx.x < o) {
            r1[threadIdx.x] += r1[threadIdx.x + o];
            r2[threadIdx.x] += r2[threadIdx.x + o];
        }
        __syncthreads();
    }
    if (threadIdx.x == 0) {
        pooled[bcd] = r1[0] / (float)HWz;
        denom[bcd]  = fmaxf(sqrtf(r2[0]), 1e-12f);
    }
}

// ---------------- Kernel 2: channel attention MLP ----------------
__global__ __launch_bounds__(128) void k_attn(const float* __restrict__ pooled,
                                              const float* __restrict__ w1,
                                              const float* __restrict__ b1,
                                              const float* __restrict__ w2,
                                              const float* __restrict__ b2,
                                              float* __restrict__ cw) {
    int bd = blockIdx.x;
    int b = bd / Dz, d = bd % Dz;
    int c = threadIdx.x;
    __shared__ float ps[Cz], hs[MIDz];
    ps[c] = pooled[(size_t)(b * Cz + c) * Dz + d];
    __syncthreads();
    if (c < MIDz) {
        float a = b1[c];
        for (int j = 0; j < Cz; j++) a += w1[c * Cz + j] * ps[j];
        hs[c] = fmaxf(a, 0.f);
    }
    __syncthreads();
    float a = b2[c];
    for (int m = 0; m < MIDz; m++) a += w2[c * MIDz + m] * hs[m];
    cw[(size_t)(b * Cz + c) * Dz + d] = 1.f / (1.f + expf(-a));
}

// ---------------- Kernel 3: s[b,d,n] = sum_c x/denom ----------------
__global__ __launch_bounds__(256) void k_s(const float* __restrict__ x,
                                           const float* __restrict__ denom,
                                           float* __restrict__ s) {
    int blk = blockIdx.x;
    int chunk = blk % NCHUNK;
    int bd = blk / NCHUNK;
    int b = bd / Dz, d = bd % Dz;
    __shared__ float rd[Cz];
    if (threadIdx.x < Cz)
        rd[threadIdx.x] = 1.f / denom[(size_t)(b * Cz + threadIdx.x) * Dz + d];
    __syncthreads();
    int n = chunk * 256 + threadIdx.x;
    if (n >= HWz) return;
    float acc = 0.f;
    const float* xp = x + ((size_t)(b * Cz) * Dz + d) * HWz + n;
    for (int c = 0; c < Cz; c++)
        acc += xp[(size_t)c * Dz * HWz] * rd[c];
    s[(size_t)bd * HWz + n] = acc;
}

// ---------------- Kernel 4: sim dot + importance ----------------
__global__ __launch_bounds__(256) void k_imp(const float* __restrict__ x,
                                             const float* __restrict__ s,
                                             const float* __restrict__ denom,
                                             const float* __restrict__ cw,
                                             const float* __restrict__ alpha,
                                             float* __restrict__ imp) {
    int bcd = blockIdx.x;
    int d = bcd % Dz;
    int b = bcd / (Cz * Dz);
    const float* xp = x + (size_t)bcd * HWz;
    const float* sp = s + ((size_t)(b * Dz) + d) * HWz;
    float acc = 0.f;
    for (int i = threadIdx.x; i < HWz; i += 256) acc += xp[i] * sp[i];
    __shared__ float r[256];
    r[threadIdx.x] = acc;
    __syncthreads();
    for (int o = 128; o > 0; o >>= 1) {
        if (threadIdx.x < o) r[threadIdx.x] += r[threadIdx.x + o];
        __syncthreads();
    }
    if (threadIdx.x == 0) {
        float sim = r[0] / (denom[bcd] * (float)Cz);
        float al = alpha[0];
        imp[bcd] = al * (1.f - sim) + (1.f - al) * cw[bcd];
    }
}

// ---------------- Kernel 5: stable top-K (descending, lower index first) ----------------
__global__ __launch_bounds__(128) void k_topk(const float* __restrict__ imp,
                                              int* __restrict__ sel,
                                              int* __restrict__ inv) {
    int bd = blockIdx.x;
    int b = bd / Dz, d = bd % Dz;
    int c = threadIdx.x;
    __shared__ float v[Cz];
    v[c] = imp[(size_t)(b * Cz + c) * Dz + d];
    __syncthreads();
    float mv = v[c];
    int rank = 0;
    for (int j = 0; j < Cz; j++) {
        float u = v[j];
        rank += (u > mv) || (u == mv && j < c);
    }
    inv[(size_t)bd * Cz + c] = (rank < Kz) ? rank : -1;
    if (rank < Kz) sel[(size_t)bd * Kz + rank] = c;
}

// ---------------- Kernel 6 v2: gathered 3x3x3 conv, LDS-tiled, register-blocked ----------
// Block: 512 threads = 8 waves. Each block: one (b, d, 8-row stripe), all 32 k outputs.
// Wave-uniform ke (tid>>6) picks 4 k's; lane pxt (tid&63) = (row 0..7, colgroup 0..7)*7 px.
// x staged per (dz, j-half): 16 planes x 10 rows x 59 cols f32 (zero-padded halo).
// Weights via wave-uniform scalar loads (SGPR operand into v_fma).
__global__ __launch_bounds__(512) void k_pconv2(const float* __restrict__ x,
                                                const float* __restrict__ wp,
                                                const int* __restrict__ sel,
                                                float* __restrict__ selected) {
    int blk = blockIdx.x;
    int rt = blk % 7;
    int bd = blk / 7;
    int d = bd % Dz, b = bd / Dz;
    int r0 = rt * 8;

    int tid = threadIdx.x;
    int ke = __builtin_amdgcn_readfirstlane(tid >> 6);   // 0..7, wave-uniform
    int pxt = tid & 63;
    int tr = pxt >> 3;        // 0..7 row within stripe
    int wg = pxt & 7;         // col group
    int w0 = wg * 7;          // first of 7 pixels

    __shared__ float xs[16][10][59];   // 37.76 KB

    float acc[4][7];
    #pragma unroll
    for (int a = 0; a < 4; a++)
        #pragma unroll
        for (int p = 0; p < 7; p++) acc[a][p] = 0.f;

    for (int dz = 0; dz < 3; dz++) {
        int dd = d + dz - 1;
        if (dd < 0 || dd >= Dz) continue;            // block-uniform
        for (int jh = 0; jh < 2; jh++) {
            __syncthreads();
            // stage 16 planes, rows r0-1..r0+8, cols -1..56 (zeros outside)
            for (int idx = tid; idx < 16 * 10 * 58; idx += 512) {
                int jj = idx / 580;
                int rem = idx - jj * 580;
                int r2 = rem / 58;
                int c = rem - r2 * 58;
                int gr = r0 + r2 - 1;
                int gw = c - 1;
                float v = 0.f;
                if (gr >= 0 && gr < Hz && gw >= 0 && gw < Wz) {
                    int ch = sel[(size_t)(b * Dz + dd) * Kz + jh * 16 + jj];
                    v = x[((size_t)(b * Cz + ch) * Dz + dd) * HWz + gr * Wz + gw];
                }
                xs[jj][r2][c] = v;
            }
            __syncthreads();
            for (int j2 = 0; j2 < 16; j2++) {
                float xr[3][9];
                #pragma unroll
                for (int dy = 0; dy < 3; dy++)
                    #pragma unroll
                    for (int c = 0; c < 9; c++)
                        xr[dy][c] = xs[j2][tr + dy][w0 + c];
                #pragma unroll
                for (int kk = 0; kk < 4; kk++) {
                    int k = ke * 4 + kk;
                    const float* wr = wp + ((size_t)k * Kz + jh * 16 + j2) * 27 + dz * 9;
                    #pragma unroll
                    for (int dy = 0; dy < 3; dy++)
                        #pragma unroll
                        for (int dx = 0; dx < 3; dx++) {
                            float wv = wr[dy * 3 + dx];
                            #pragma unroll
                            for (int p = 0; p < 7; p++)
                                acc[kk][p] += wv * xr[dy][dx + p];
                        }
                }
            }
        }
    }
    int k0 = ke * 4;
    #pragma unroll
    for (int kk = 0; kk < 4; kk++) {
        size_t base = ((size_t)(b * Kz + k0 + kk) * Dz + d) * HWz + (r0 + tr) * Wz + w0;
        #pragma unroll
        for (int p = 0; p < 7; p++)
            selected[base + p] = acc[kk][p];
    }
}

// ---------------- Kernel 7: depthwise conv + BN + ReLU -> d_out ----------------
__global__ __launch_bounds__(256) void k_dw(const float* __restrict__ x,
                                            const float* __restrict__ selected,
                                            const int* __restrict__ inv,
                                            const float* __restrict__ dww,
                                            const float* __restrict__ gam,
                                            const float* __restrict__ bet,
                                            const float* __restrict__ mn,
                                            const float* __restrict__ vr,
                                            float* __restrict__ out) {
    int blk = blockIdx.x;
    int chunk = blk % NCHUNK;
    int rest = blk / NCHUNK;
    int d = rest % Dz; rest /= Dz;
    int c = rest % Cz;
    int b = rest / Cz;
    int p = chunk * 256 + threadIdx.x;
    if (p >= HWz) return;
    int h = p / Wz, w = p % Wz;
    int y0 = (h == 0) ? 1 : 0, y1 = (h == Hz - 1) ? 2 : 3;
    int x0 = (w == 0) ? 1 : 0, x1 = (w == Wz - 1) ? 2 : 3;

    float acc = 0.f;
    for (int dz = 0; dz < 3; dz++) {
        int dd = d + dz - 1;
        if (dd < 0 || dd >= Dz) continue;
        int pos = inv[(size_t)(b * Dz + dd) * Cz + c];
        const float* src = (pos >= 0)
            ? selected + ((size_t)(b * Kz + pos) * Dz + dd) * HWz
            : x + ((size_t)(b * Cz + c) * Dz + dd) * HWz;
        const float* wrow = dww + c * 27 + dz * 9;
        for (int dy = y0; dy < y1; dy++) {
            const float* xr = src + (h + dy - 1) * Wz + (w - 1);
            const float* wr = wrow + dy * 3;
            #pragma unroll
            for (int dx = 0; dx < 3; dx++) {
                if (dx >= x0 && dx < x1) acc += wr[dx] * xr[dx];
            }
        }
    }
    float sc = gam[c] * (1.f / sqrtf(vr[c] + 1e-5f));
    float v = (acc - mn[c]) * sc + bet[c];
    out[((size_t)(b * Cz + c) * Dz + d) * HWz + p] = fmaxf(v, 0.f);
}

// ---------------- Kernel 8: in-place pointwise 128x128 GEMM on d_out ----------------
__global__ __launch_bounds__(256) void k_pw(const float* __restrict__ pw,
                                            float* __restrict__ out) {
    int blk = blockIdx.x;
    int tile = blk % 49;           // 3136 / 64
    int bd = blk / 49;
    int b = bd / Dz, d = bd % Dz;
    __shared__ float yt[Cz][64];
    size_t base = ((size_t)(b * Cz) * Dz + d) * HWz + tile * 64;
    for (int i = threadIdx.x; i < Cz * 64; i += 256) {
        int c = i >> 6, p = i & 63;
        yt[c][p] = out[base + (size_t)c * Dz * HWz + p];
    }
    __syncthreads();
    int g = threadIdx.x >> 6, p = threadIdx.x & 63;
    for (int og = 0; og < 32; og++) {
        int o = g * 32 + og;
        const float* wrow = pw + (size_t)o * Cz;
        float acc = 0.f;
        #pragma unroll 8
        for (int c = 0; c < Cz; c++) acc += wrow[c] * yt[c][p];
        out[base + (size_t)o * Dz * HWz + p] = acc;
    }
}

extern "C" void kernel_launch(void* const* d_in, const int* in_sizes, int n_in,
                              void* d_out, int out_size, void* d_ws, size_t ws_size,
                              hipStream_t stream) {
    const float* x     = (const float*)d_in[0];
    const float* wp    = (const float*)d_in[1];
    const float* ca_w1 = (const float*)d_in[2];
    const float* ca_b1 = (const float*)d_in[3];
    const float* ca_w2 = (const float*)d_in[4];
    const float* ca_b2 = (const float*)d_in[5];
    const float* alpha = (const float*)d_in[6];
    const float* dw_w  = (const float*)d_in[7];
    const float* bn_g  = (const float*)d_in[8];
    const float* bn_b  = (const float*)d_in[9];
    const float* bn_m  = (const float*)d_in[10];
    const float* bn_v  = (const float*)d_in[11];
    const float* pw_w  = (const float*)d_in[12];

    float* ws = (float*)d_ws;
    float* pooled   = ws + OFF_POOLED;
    float* denom    = ws + OFF_DENOM;
    float* cw       = ws + OFF_CW;
    float* imp      = ws + OFF_IMP;
    float* s        = ws + OFF_S;
    int*   sel      = (int*)(ws + OFF_SEL);
    int*   inv      = (int*)(ws + OFF_INV);
    float* selected = ws + OFF_SELECTED;
    float* out      = (float*)d_out;

    k_stats<<<Bz * Cz * Dz, 256, 0, stream>>>(x, pooled, denom);
    k_attn<<<Bz * Dz, 128, 0, stream>>>(pooled, ca_w1, ca_b1, ca_w2, ca_b2, cw);
    k_s<<<Bz * Dz * NCHUNK, 256, 0, stream>>>(x, denom, s);
    k_imp<<<Bz * Cz * Dz, 256, 0, stream>>>(x, s, denom, cw, alpha, imp);
    k_topk<<<Bz * Dz, 128, 0, stream>>>(imp, sel, inv);
    k_pconv2<<<Bz * Dz * 7, 512, 0, stream>>>(x, wp, sel, selected);
    k_dw<<<Bz * Cz * Dz * NCHUNK, 256, 0, stream>>>(x, selected, inv, dw_w,
                                                    bn_g, bn_b, bn_m, bn_v, out);
    k_pw<<<Bz * Dz * 49, 256, 0, stream>>>(pw_w, out);
}

// Round 4
// 911.692 us; speedup vs baseline: 2.9152x; 1.3838x over previous
//
#include <hip/hip_runtime.h>
#include <hip/hip_bf16.h>
#include <math.h>

// Problem constants
constexpr int Bz = 4, Cz = 128, Dz = 16, Hz = 56, Wz = 56;
constexpr int Kz = 32, MIDz = 32;
constexpr int HWz = Hz * Wz;           // 3136
constexpr int NCHUNK = (HWz + 255) / 256; // 13

// Workspace layout (float offsets)
constexpr size_t OFF_POOLED   = 0;                       // 8192
constexpr size_t OFF_DENOM    = 8192;                    // 8192
constexpr size_t OFF_CW       = 16384;                   // 8192
constexpr size_t OFF_IMP      = 24576;                   // 8192
constexpr size_t OFF_S        = 32768;                   // 200704
constexpr size_t OFF_SEL      = 233472;                  // 2048 ints
constexpr size_t OFF_INV      = 235520;                  // 8192 ints
constexpr size_t OFF_SELECTED = 243712;                  // 6422528 floats
constexpr size_t OFF_PWT      = 6666240;                 // 16384 floats

// ---------------- Kernel 1: per-(b,c,d) mean and L2 norm ----------------
__global__ __launch_bounds__(256) void k_stats(const float* __restrict__ x,
                                               float* __restrict__ pooled,
                                               float* __restrict__ denom) {
    int bcd = blockIdx.x;
    const float* p = x + (size_t)bcd * HWz;
    float s = 0.f, ss = 0.f;
    for (int i = threadIdx.x; i < HWz; i += 256) {
        float v = p[i];
        s += v; ss += v * v;
    }
    __shared__ float r1[256], r2[256];
    r1[threadIdx.x] = s; r2[threadIdx.x] = ss;
    __syncthreads();
    for (int o = 128; o > 0; o >>= 1) {
        if (threadIdx.x < o) {
            r1[threadIdx.x] += r1[threadIdx.x + o];
            r2[threadIdx.x] += r2[threadIdx.x + o];
        }
        __syncthreads();
    }
    if (threadIdx.x == 0) {
        pooled[bcd] = r1[0] / (float)HWz;
        denom[bcd]  = fmaxf(sqrtf(r2[0]), 1e-12f);
    }
}

// ---------------- Kernel 2: channel attention MLP ----------------
__global__ __launch_bounds__(128) void k_attn(const float* __restrict__ pooled,
                                              const float* __restrict__ w1,
                                              const float* __restrict__ b1,
                                              const float* __restrict__ w2,
                                              const float* __restrict__ b2,
                                              float* __restrict__ cw) {
    int bd = blockIdx.x;
    int b = bd / Dz, d = bd % Dz;
    int c = threadIdx.x;
    __shared__ float ps[Cz], hs[MIDz];
    ps[c] = pooled[(size_t)(b * Cz + c) * Dz + d];
    __syncthreads();
    if (c < MIDz) {
        float a = b1[c];
        for (int j = 0; j < Cz; j++) a += w1[c * Cz + j] * ps[j];
        hs[c] = fmaxf(a, 0.f);
    }
    __syncthreads();
    float a = b2[c];
    for (int m = 0; m < MIDz; m++) a += w2[c * MIDz + m] * hs[m];
    cw[(size_t)(b * Cz + c) * Dz + d] = 1.f / (1.f + expf(-a));
}

// ---------------- Kernel 3: s[b,d,n] = sum_c x/denom ----------------
__global__ __launch_bounds__(256) void k_s(const float* __restrict__ x,
                                           const float* __restrict__ denom,
                                           float* __restrict__ s) {
    int blk = blockIdx.x;
    int chunk = blk % NCHUNK;
    int bd = blk / NCHUNK;
    int b = bd / Dz, d = bd % Dz;
    __shared__ float rd[Cz];
    if (threadIdx.x < Cz)
        rd[threadIdx.x] = 1.f / denom[(size_t)(b * Cz + threadIdx.x) * Dz + d];
    __syncthreads();
    int n = chunk * 256 + threadIdx.x;
    if (n >= HWz) return;
    float acc = 0.f;
    const float* xp = x + ((size_t)(b * Cz) * Dz + d) * HWz + n;
    for (int c = 0; c < Cz; c++)
        acc += xp[(size_t)c * Dz * HWz] * rd[c];
    s[(size_t)bd * HWz + n] = acc;
}

// ---------------- Kernel 4: sim dot + importance ----------------
__global__ __launch_bounds__(256) void k_imp(const float* __restrict__ x,
                                             const float* __restrict__ s,
                                             const float* __restrict__ denom,
                                             const float* __restrict__ cw,
                                             const float* __restrict__ alpha,
                                             float* __restrict__ imp) {
    int bcd = blockIdx.x;
    int d = bcd % Dz;
    int b = bcd / (Cz * Dz);
    const float* xp = x + (size_t)bcd * HWz;
    const float* sp = s + ((size_t)(b * Dz) + d) * HWz;
    float acc = 0.f;
    for (int i = threadIdx.x; i < HWz; i += 256) acc += xp[i] * sp[i];
    __shared__ float r[256];
    r[threadIdx.x] = acc;
    __syncthreads();
    for (int o = 128; o > 0; o >>= 1) {
        if (threadIdx.x < o) r[threadIdx.x] += r[threadIdx.x + o];
        __syncthreads();
    }
    if (threadIdx.x == 0) {
        float sim = r[0] / (denom[bcd] * (float)Cz);
        float al = alpha[0];
        imp[bcd] = al * (1.f - sim) + (1.f - al) * cw[bcd];
    }
}

// ---------------- Kernel 5: stable top-K (descending, lower index first) ----------------
__global__ __launch_bounds__(128) void k_topk(const float* __restrict__ imp,
                                              int* __restrict__ sel,
                                              int* __restrict__ inv) {
    int bd = blockIdx.x;
    int b = bd / Dz, d = bd % Dz;
    int c = threadIdx.x;
    __shared__ float v[Cz];
    v[c] = imp[(size_t)(b * Cz + c) * Dz + d];
    __syncthreads();
    float mv = v[c];
    int rank = 0;
    for (int j = 0; j < Cz; j++) {
        float u = v[j];
        rank += (u > mv) || (u == mv && j < c);
    }
    inv[(size_t)bd * Cz + c] = (rank < Kz) ? rank : -1;
    if (rank < Kz) sel[(size_t)bd * Kz + rank] = c;
}

// ---------------- Kernel 6 v2: gathered 3x3x3 conv, LDS-tiled, register-blocked ----------
__global__ __launch_bounds__(512) void k_pconv2(const float* __restrict__ x,
                                                const float* __restrict__ wp,
                                                const int* __restrict__ sel,
                                                float* __restrict__ selected) {
    int blk = blockIdx.x;
    int rt = blk % 7;
    int bd = blk / 7;
    int d = bd % Dz, b = bd / Dz;
    int r0 = rt * 8;

    int tid = threadIdx.x;
    int ke = __builtin_amdgcn_readfirstlane(tid >> 6);   // 0..7, wave-uniform
    int pxt = tid & 63;
    int tr = pxt >> 3;        // 0..7 row within stripe
    int wg = pxt & 7;         // col group
    int w0 = wg * 7;          // first of 7 pixels

    __shared__ float xs[16][10][59];   // 37.76 KB

    float acc[4][7];
    #pragma unroll
    for (int a = 0; a < 4; a++)
        #pragma unroll
        for (int p = 0; p < 7; p++) acc[a][p] = 0.f;

    for (int dz = 0; dz < 3; dz++) {
        int dd = d + dz - 1;
        if (dd < 0 || dd >= Dz) continue;            // block-uniform
        for (int jh = 0; jh < 2; jh++) {
            __syncthreads();
            for (int idx = tid; idx < 16 * 10 * 58; idx += 512) {
                int jj = idx / 580;
                int rem = idx - jj * 580;
                int r2 = rem / 58;
                int c = rem - r2 * 58;
                int gr = r0 + r2 - 1;
                int gw = c - 1;
                float v = 0.f;
                if (gr >= 0 && gr < Hz && gw >= 0 && gw < Wz) {
                    int ch = sel[(size_t)(b * Dz + dd) * Kz + jh * 16 + jj];
                    v = x[((size_t)(b * Cz + ch) * Dz + dd) * HWz + gr * Wz + gw];
                }
                xs[jj][r2][c] = v;
            }
            __syncthreads();
            for (int j2 = 0; j2 < 16; j2++) {
                float xr[3][9];
                #pragma unroll
                for (int dy = 0; dy < 3; dy++)
                    #pragma unroll
                    for (int c = 0; c < 9; c++)
                        xr[dy][c] = xs[j2][tr + dy][w0 + c];
                #pragma unroll
                for (int kk = 0; kk < 4; kk++) {
                    int k = ke * 4 + kk;
                    const float* wr = wp + ((size_t)k * Kz + jh * 16 + j2) * 27 + dz * 9;
                    #pragma unroll
                    for (int dy = 0; dy < 3; dy++)
                        #pragma unroll
                        for (int dx = 0; dx < 3; dx++) {
                            float wv = wr[dy * 3 + dx];
                            #pragma unroll
                            for (int p = 0; p < 7; p++)
                                acc[kk][p] += wv * xr[dy][dx + p];
                        }
                }
            }
        }
    }
    int k0 = ke * 4;
    #pragma unroll
    for (int kk = 0; kk < 4; kk++) {
        size_t base = ((size_t)(b * Kz + k0 + kk) * Dz + d) * HWz + (r0 + tr) * Wz + w0;
        #pragma unroll
        for (int p = 0; p < 7; p++)
            selected[base + p] = acc[kk][p];
    }
}

// ---------------- Kernel 7: depthwise conv + BN + ReLU -> d_out ----------------
__global__ __launch_bounds__(256) void k_dw(const float* __restrict__ x,
                                            const float* __restrict__ selected,
                                            const int* __restrict__ inv,
                                            const float* __restrict__ dww,
                                            const float* __restrict__ gam,
                                            const float* __restrict__ bet,
                                            const float* __restrict__ mn,
                                            const float* __restrict__ vr,
                                            float* __restrict__ out) {
    int blk = blockIdx.x;
    int chunk = blk % NCHUNK;
    int rest = blk / NCHUNK;
    int d = rest % Dz; rest /= Dz;
    int c = rest % Cz;
    int b = rest / Cz;
    int p = chunk * 256 + threadIdx.x;
    if (p >= HWz) return;
    int h = p / Wz, w = p % Wz;
    int y0 = (h == 0) ? 1 : 0, y1 = (h == Hz - 1) ? 2 : 3;
    int x0 = (w == 0) ? 1 : 0, x1 = (w == Wz - 1) ? 2 : 3;

    float acc = 0.f;
    for (int dz = 0; dz < 3; dz++) {
        int dd = d + dz - 1;
        if (dd < 0 || dd >= Dz) continue;
        int pos = inv[(size_t)(b * Dz + dd) * Cz + c];
        const float* src = (pos >= 0)
            ? selected + ((size_t)(b * Kz + pos) * Dz + dd) * HWz
            : x + ((size_t)(b * Cz + c) * Dz + dd) * HWz;
        const float* wrow = dww + c * 27 + dz * 9;
        for (int dy = y0; dy < y1; dy++) {
            const float* xr = src + (h + dy - 1) * Wz + (w - 1);
            const float* wr = wrow + dy * 3;
            #pragma unroll
            for (int dx = 0; dx < 3; dx++) {
                if (dx >= x0 && dx < x1) acc += wr[dx] * xr[dx];
            }
        }
    }
    float sc = gam[c] * (1.f / sqrtf(vr[c] + 1e-5f));
    float v = (acc - mn[c]) * sc + bet[c];
    out[((size_t)(b * Cz + c) * Dz + d) * HWz + p] = fmaxf(v, 0.f);
}

// ---------------- Kernel 8a: transpose pw -> pwT[c][o] ----------------
__global__ __launch_bounds__(256) void k_pwT(const float* __restrict__ pw,
                                             float* __restrict__ pwT) {
    int i = blockIdx.x * 256 + threadIdx.x;   // 16384 total
    int o = i >> 7, c = i & 127;
    pwT[c * Cz + o] = pw[o * Cz + c];
}

// ---------------- Kernel 8b: in-place pointwise GEMM, scalar-pipe weights ----------
// Block: 256 thr = 4 o-groups x 64 px. Per c-step: 1 LDS read (y) + 32 FMA whose
// weight row (contiguous 128B, wave-uniform) comes via s_load -> SGPR operands.
__global__ __launch_bounds__(256) void k_pw2(const float* __restrict__ pwT,
                                             float* __restrict__ out) {
    int blk = blockIdx.x;
    int tile = blk % 49;           // 3136 / 64
    int bd = blk / 49;
    int b = bd / Dz, d = bd % Dz;
    __shared__ float yt[Cz][64];
    size_t base = ((size_t)(b * Cz) * Dz + d) * HWz + tile * 64;
    for (int i = threadIdx.x; i < Cz * 64; i += 256) {
        int c = i >> 6, p = i & 63;
        yt[c][p] = out[base + (size_t)c * Dz * HWz + p];
    }
    __syncthreads();
    int g = __builtin_amdgcn_readfirstlane(threadIdx.x >> 6);  // 0..3 wave-uniform
    int p = threadIdx.x & 63;
    float acc[32];
    #pragma unroll
    for (int j = 0; j < 32; j++) acc[j] = 0.f;
    const float* wbase = pwT + g * 32;
    #pragma unroll 2
    for (int c = 0; c < Cz; c++) {
        float yv = yt[c][p];
        const float* wr = wbase + (size_t)c * Cz;
        #pragma unroll
        for (int j = 0; j < 32; j++) acc[j] = fmaf(wr[j], yv, acc[j]);
    }
    #pragma unroll
    for (int j = 0; j < 32; j++)
        out[base + (size_t)(g * 32 + j) * Dz * HWz + p] = acc[j];
}

extern "C" void kernel_launch(void* const* d_in, const int* in_sizes, int n_in,
                              void* d_out, int out_size, void* d_ws, size_t ws_size,
                              hipStream_t stream) {
    const float* x     = (const float*)d_in[0];
    const float* wp    = (const float*)d_in[1];
    const float* ca_w1 = (const float*)d_in[2];
    const float* ca_b1 = (const float*)d_in[3];
    const float* ca_w2 = (const float*)d_in[4];
    const float* ca_b2 = (const float*)d_in[5];
    const float* alpha = (const float*)d_in[6];
    const float* dw_w  = (const float*)d_in[7];
    const float* bn_g  = (const float*)d_in[8];
    const float* bn_b  = (const float*)d_in[9];
    const float* bn_m  = (const float*)d_in[10];
    const float* bn_v  = (const float*)d_in[11];
    const float* pw_w  = (const float*)d_in[12];

    float* ws = (float*)d_ws;
    float* pooled   = ws + OFF_POOLED;
    float* denom    = ws + OFF_DENOM;
    float* cw       = ws + OFF_CW;
    float* imp      = ws + OFF_IMP;
    float* s        = ws + OFF_S;
    int*   sel      = (int*)(ws + OFF_SEL);
    int*   inv      = (int*)(ws + OFF_INV);
    float* selected = ws + OFF_SELECTED;
    float* pwT      = ws + OFF_PWT;
    float* out      = (float*)d_out;

    k_stats<<<Bz * Cz * Dz, 256, 0, stream>>>(x, pooled, denom);
    k_attn<<<Bz * Dz, 128, 0, stream>>>(pooled, ca_w1, ca_b1, ca_w2, ca_b2, cw);
    k_s<<<Bz * Dz * NCHUNK, 256, 0, stream>>>(x, denom, s);
    k_imp<<<Bz * Cz * Dz, 256, 0, stream>>>(x, s, denom, cw, alpha, imp);
    k_topk<<<Bz * Dz, 128, 0, stream>>>(imp, sel, inv);
    k_pwT<<<64, 256, 0, stream>>>(pw_w, pwT);
    k_pconv2<<<Bz * Dz * 7, 512, 0, stream>>>(x, wp, sel, selected);
    k_dw<<<Bz * Cz * Dz * NCHUNK, 256, 0, stream>>>(x, selected, inv, dw_w,
                                                    bn_g, bn_b, bn_m, bn_v, out);
    k_pw2<<<Bz * Dz * 49, 256, 0, stream>>>(pwT, out);
}

// Round 5
// 710.825 us; speedup vs baseline: 3.7390x; 1.2826x over previous
//
#include <hip/hip_runtime.h>
#include <hip/hip_bf16.h>
#include <math.h>

// Problem constants
constexpr int Bz = 4, Cz = 128, Dz = 16, Hz = 56, Wz = 56;
constexpr int Kz = 32, MIDz = 32;
constexpr int HWz = Hz * Wz;           // 3136
constexpr int NCHUNK = (HWz + 255) / 256; // 13

// Workspace layout (float offsets)
constexpr size_t OFF_POOLED   = 0;                       // 8192
constexpr size_t OFF_DENOM    = 8192;                    // 8192
constexpr size_t OFF_CW       = 16384;                   // 8192
constexpr size_t OFF_IMP      = 24576;                   // 8192
constexpr size_t OFF_S        = 32768;                   // 200704
constexpr size_t OFF_SEL      = 233472;                  // 2048 ints
constexpr size_t OFF_INV      = 235520;                  // 8192 ints
constexpr size_t OFF_SELECTED = 243712;                  // 6422528 floats
constexpr size_t OFF_PWT      = 6666240;                 // 16384 floats

// ---------------- Kernel 1: per-(b,c,d) mean and L2 norm ----------------
__global__ __launch_bounds__(256) void k_stats(const float* __restrict__ x,
                                               float* __restrict__ pooled,
                                               float* __restrict__ denom) {
    int bcd = blockIdx.x;
    const float* p = x + (size_t)bcd * HWz;
    float s = 0.f, ss = 0.f;
    for (int i = threadIdx.x; i < HWz; i += 256) {
        float v = p[i];
        s += v; ss += v * v;
    }
    __shared__ float r1[256], r2[256];
    r1[threadIdx.x] = s; r2[threadIdx.x] = ss;
    __syncthreads();
    for (int o = 128; o > 0; o >>= 1) {
        if (threadIdx.x < o) {
            r1[threadIdx.x] += r1[threadIdx.x + o];
            r2[threadIdx.x] += r2[threadIdx.x + o];
        }
        __syncthreads();
    }
    if (threadIdx.x == 0) {
        pooled[bcd] = r1[0] / (float)HWz;
        denom[bcd]  = fmaxf(sqrtf(r2[0]), 1e-12f);
    }
}

// ---------------- Kernel 2: channel attention MLP ----------------
__global__ __launch_bounds__(128) void k_attn(const float* __restrict__ pooled,
                                              const float* __restrict__ w1,
                                              const float* __restrict__ b1,
                                              const float* __restrict__ w2,
                                              const float* __restrict__ b2,
                                              float* __restrict__ cw) {
    int bd = blockIdx.x;
    int b = bd / Dz, d = bd % Dz;
    int c = threadIdx.x;
    __shared__ float ps[Cz], hs[MIDz];
    ps[c] = pooled[(size_t)(b * Cz + c) * Dz + d];
    __syncthreads();
    if (c < MIDz) {
        float a = b1[c];
        for (int j = 0; j < Cz; j++) a += w1[c * Cz + j] * ps[j];
        hs[c] = fmaxf(a, 0.f);
    }
    __syncthreads();
    float a = b2[c];
    for (int m = 0; m < MIDz; m++) a += w2[c * MIDz + m] * hs[m];
    cw[(size_t)(b * Cz + c) * Dz + d] = 1.f / (1.f + expf(-a));
}

// ---------------- Kernel 3: s[b,d,n] = sum_c x/denom ----------------
__global__ __launch_bounds__(256) void k_s(const float* __restrict__ x,
                                           const float* __restrict__ denom,
                                           float* __restrict__ s) {
    int blk = blockIdx.x;
    int chunk = blk % NCHUNK;
    int bd = blk / NCHUNK;
    int b = bd / Dz, d = bd % Dz;
    __shared__ float rd[Cz];
    if (threadIdx.x < Cz)
        rd[threadIdx.x] = 1.f / denom[(size_t)(b * Cz + threadIdx.x) * Dz + d];
    __syncthreads();
    int n = chunk * 256 + threadIdx.x;
    if (n >= HWz) return;
    float acc = 0.f;
    const float* xp = x + ((size_t)(b * Cz) * Dz + d) * HWz + n;
    for (int c = 0; c < Cz; c++)
        acc += xp[(size_t)c * Dz * HWz] * rd[c];
    s[(size_t)bd * HWz + n] = acc;
}

// ---------------- Kernel 4: sim dot + importance ----------------
__global__ __launch_bounds__(256) void k_imp(const float* __restrict__ x,
                                             const float* __restrict__ s,
                                             const float* __restrict__ denom,
                                             const float* __restrict__ cw,
                                             const float* __restrict__ alpha,
                                             float* __restrict__ imp) {
    int bcd = blockIdx.x;
    int d = bcd % Dz;
    int b = bcd / (Cz * Dz);
    const float* xp = x + (size_t)bcd * HWz;
    const float* sp = s + ((size_t)(b * Dz) + d) * HWz;
    float acc = 0.f;
    for (int i = threadIdx.x; i < HWz; i += 256) acc += xp[i] * sp[i];
    __shared__ float r[256];
    r[threadIdx.x] = acc;
    __syncthreads();
    for (int o = 128; o > 0; o >>= 1) {
        if (threadIdx.x < o) r[threadIdx.x] += r[threadIdx.x + o];
        __syncthreads();
    }
    if (threadIdx.x == 0) {
        float sim = r[0] / (denom[bcd] * (float)Cz);
        float al = alpha[0];
        imp[bcd] = al * (1.f - sim) + (1.f - al) * cw[bcd];
    }
}

// ---------------- Kernel 5: stable top-K (descending, lower index first) ----------------
__global__ __launch_bounds__(128) void k_topk(const float* __restrict__ imp,
                                              int* __restrict__ sel,
                                              int* __restrict__ inv) {
    int bd = blockIdx.x;
    int b = bd / Dz, d = bd % Dz;
    int c = threadIdx.x;
    __shared__ float v[Cz];
    v[c] = imp[(size_t)(b * Cz + c) * Dz + d];
    __syncthreads();
    float mv = v[c];
    int rank = 0;
    for (int j = 0; j < Cz; j++) {
        float u = v[j];
        rank += (u > mv) || (u == mv && j < c);
    }
    inv[(size_t)bd * Cz + c] = (rank < Kz) ? rank : -1;
    if (rank < Kz) sel[(size_t)bd * Kz + rank] = c;
}

// ---------------- Kernel 6 v2: gathered 3x3x3 conv, LDS-tiled, register-blocked ----------
__global__ __launch_bounds__(512) void k_pconv2(const float* __restrict__ x,
                                                const float* __restrict__ wp,
                                                const int* __restrict__ sel,
                                                float* __restrict__ selected) {
    int blk = blockIdx.x;
    int rt = blk % 7;
    int bd = blk / 7;
    int d = bd % Dz, b = bd / Dz;
    int r0 = rt * 8;

    int tid = threadIdx.x;
    int ke = __builtin_amdgcn_readfirstlane(tid >> 6);   // 0..7, wave-uniform
    int pxt = tid & 63;
    int tr = pxt >> 3;        // 0..7 row within stripe
    int wg = pxt & 7;         // col group
    int w0 = wg * 7;          // first of 7 pixels

    __shared__ float xs[16][10][59];   // 37.76 KB

    float acc[4][7];
    #pragma unroll
    for (int a = 0; a < 4; a++)
        #pragma unroll
        for (int p = 0; p < 7; p++) acc[a][p] = 0.f;

    for (int dz = 0; dz < 3; dz++) {
        int dd = d + dz - 1;
        if (dd < 0 || dd >= Dz) continue;            // block-uniform
        for (int jh = 0; jh < 2; jh++) {
            __syncthreads();
            for (int idx = tid; idx < 16 * 10 * 58; idx += 512) {
                int jj = idx / 580;
                int rem = idx - jj * 580;
                int r2 = rem / 58;
                int c = rem - r2 * 58;
                int gr = r0 + r2 - 1;
                int gw = c - 1;
                float v = 0.f;
                if (gr >= 0 && gr < Hz && gw >= 0 && gw < Wz) {
                    int ch = sel[(size_t)(b * Dz + dd) * Kz + jh * 16 + jj];
                    v = x[((size_t)(b * Cz + ch) * Dz + dd) * HWz + gr * Wz + gw];
                }
                xs[jj][r2][c] = v;
            }
            __syncthreads();
            for (int j2 = 0; j2 < 16; j2++) {
                float xr[3][9];
                #pragma unroll
                for (int dy = 0; dy < 3; dy++)
                    #pragma unroll
                    for (int c = 0; c < 9; c++)
                        xr[dy][c] = xs[j2][tr + dy][w0 + c];
                #pragma unroll
                for (int kk = 0; kk < 4; kk++) {
                    int k = ke * 4 + kk;
                    const float* wr = wp + ((size_t)k * Kz + jh * 16 + j2) * 27 + dz * 9;
                    #pragma unroll
                    for (int dy = 0; dy < 3; dy++)
                        #pragma unroll
                        for (int dx = 0; dx < 3; dx++) {
                            float wv = wr[dy * 3 + dx];
                            #pragma unroll
                            for (int p = 0; p < 7; p++)
                                acc[kk][p] += wv * xr[dy][dx + p];
                        }
                }
            }
        }
    }
    int k0 = ke * 4;
    #pragma unroll
    for (int kk = 0; kk < 4; kk++) {
        size_t base = ((size_t)(b * Kz + k0 + kk) * Dz + d) * HWz + (r0 + tr) * Wz + w0;
        #pragma unroll
        for (int p = 0; p < 7; p++)
            selected[base + p] = acc[kk][p];
    }
}

// ---------------- Kernel 7 v2: depthwise conv + BN + ReLU, register-blocked ----------
// One block per (b,c,d); 448 threads = (row 0..55, colgroup 0..7) x 7 px each.
// All 81 window loads unrolled & predicated -> deep MLP; weights/base ptrs uniform.
__global__ __launch_bounds__(448) void k_dw2(const float* __restrict__ x,
                                             const float* __restrict__ selected,
                                             const int* __restrict__ inv,
                                             const float* __restrict__ dww,
                                             const float* __restrict__ gam,
                                             const float* __restrict__ bet,
                                             const float* __restrict__ mn,
                                             const float* __restrict__ vr,
                                             float* __restrict__ out) {
    int bcd = blockIdx.x;                 // (b*Cz + c)*Dz + d
    int d = bcd % Dz;
    int c = (bcd / Dz) % Cz;
    int b = bcd / (Dz * Cz);
    int tid = threadIdx.x;
    int h = tid >> 3;                     // 0..55
    int wg = tid & 7;                     // 0..7
    int w0 = wg * 7;

    // per-plane source pointers (block-uniform -> SGPR)
    const float* src0 = x; const float* src1 = x; const float* src2 = x;
    bool v0 = false, v1 = true, v2 = false;
    {
        int dd = d - 1;
        if (dd >= 0) {
            int pos = inv[(size_t)(b * Dz + dd) * Cz + c];
            src0 = (pos >= 0) ? selected + ((size_t)(b * Kz + pos) * Dz + dd) * HWz
                              : x + ((size_t)(b * Cz + c) * Dz + dd) * HWz;
            v0 = true;
        }
    }
    {
        int pos = inv[(size_t)(b * Dz + d) * Cz + c];
        src1 = (pos >= 0) ? selected + ((size_t)(b * Kz + pos) * Dz + d) * HWz
                          : x + ((size_t)(b * Cz + c) * Dz + d) * HWz;
    }
    {
        int dd = d + 1;
        if (dd < Dz) {
            int pos = inv[(size_t)(b * Dz + dd) * Cz + c];
            src2 = (pos >= 0) ? selected + ((size_t)(b * Kz + pos) * Dz + dd) * HWz
                              : x + ((size_t)(b * Cz + c) * Dz + dd) * HWz;
            v2 = true;
        }
    }
    const float* srcs[3] = {src0, src1, src2};
    bool vs[3] = {v0, v1, v2};

    // window loads: vv[dz][dy][0..8], fully unrolled, predicated
    float vv[3][3][9];
    #pragma unroll
    for (int dz = 0; dz < 3; dz++) {
        #pragma unroll
        for (int dy = 0; dy < 3; dy++) {
            int hh = h + dy - 1;
            bool rowok = vs[dz] && ((unsigned)hh < (unsigned)Hz);
            const float* rp = srcs[dz] + hh * Wz + (w0 - 1);
            #pragma unroll
            for (int i = 0; i < 9; i++) {
                bool ok = rowok && ((unsigned)(w0 - 1 + i) < (unsigned)Wz);
                vv[dz][dy][i] = ok ? rp[i] : 0.f;
            }
        }
    }

    // weights (block-uniform -> s_load)
    const float* wr = dww + c * 27;
    float acc[7];
    #pragma unroll
    for (int p = 0; p < 7; p++) acc[p] = 0.f;
    #pragma unroll
    for (int dz = 0; dz < 3; dz++)
        #pragma unroll
        for (int dy = 0; dy < 3; dy++)
            #pragma unroll
            for (int dx = 0; dx < 3; dx++) {
                float wv = wr[dz * 9 + dy * 3 + dx];
                #pragma unroll
                for (int p = 0; p < 7; p++)
                    acc[p] = fmaf(wv, vv[dz][dy][dx + p], acc[p]);
            }

    float sc = gam[c] * (1.f / sqrtf(vr[c] + 1e-5f));
    float mb = mn[c], bb = bet[c];
    size_t base = ((size_t)(b * Cz + c) * Dz + d) * HWz + h * Wz + w0;
    #pragma unroll
    for (int p = 0; p < 7; p++)
        out[base + p] = fmaxf((acc[p] - mb) * sc + bb, 0.f);
}

// ---------------- Kernel 8a: transpose pw -> pwT[c][o] ----------------
__global__ __launch_bounds__(256) void k_pwT(const float* __restrict__ pw,
                                             float* __restrict__ pwT) {
    int i = blockIdx.x * 256 + threadIdx.x;   // 16384 total
    int o = i >> 7, c = i & 127;
    pwT[c * Cz + o] = pw[o * Cz + c];
}

// ---------------- Kernel 8b: in-place pointwise GEMM, scalar-pipe weights ----------
__global__ __launch_bounds__(256) void k_pw2(const float* __restrict__ pwT,
                                             float* __restrict__ out) {
    int blk = blockIdx.x;
    int tile = blk % 49;           // 3136 / 64
    int bd = blk / 49;
    int b = bd / Dz, d = bd % Dz;
    __shared__ float yt[Cz][64];
    size_t base = ((size_t)(b * Cz) * Dz + d) * HWz + tile * 64;
    for (int i = threadIdx.x; i < Cz * 64; i += 256) {
        int c = i >> 6, p = i & 63;
        yt[c][p] = out[base + (size_t)c * Dz * HWz + p];
    }
    __syncthreads();
    int g = __builtin_amdgcn_readfirstlane(threadIdx.x >> 6);  // 0..3 wave-uniform
    int p = threadIdx.x & 63;
    float acc[32];
    #pragma unroll
    for (int j = 0; j < 32; j++) acc[j] = 0.f;
    const float* wbase = pwT + g * 32;
    #pragma unroll 2
    for (int c = 0; c < Cz; c++) {
        float yv = yt[c][p];
        const float* wr = wbase + (size_t)c * Cz;
        #pragma unroll
        for (int j = 0; j < 32; j++) acc[j] = fmaf(wr[j], yv, acc[j]);
    }
    #pragma unroll
    for (int j = 0; j < 32; j++)
        out[base + (size_t)(g * 32 + j) * Dz * HWz + p] = acc[j];
}

extern "C" void kernel_launch(void* const* d_in, const int* in_sizes, int n_in,
                              void* d_out, int out_size, void* d_ws, size_t ws_size,
                              hipStream_t stream) {
    const float* x     = (const float*)d_in[0];
    const float* wp    = (const float*)d_in[1];
    const float* ca_w1 = (const float*)d_in[2];
    const float* ca_b1 = (const float*)d_in[3];
    const float* ca_w2 = (const float*)d_in[4];
    const float* ca_b2 = (const float*)d_in[5];
    const float* alpha = (const float*)d_in[6];
    const float* dw_w  = (const float*)d_in[7];
    const float* bn_g  = (const float*)d_in[8];
    const float* bn_b  = (const float*)d_in[9];
    const float* bn_m  = (const float*)d_in[10];
    const float* bn_v  = (const float*)d_in[11];
    const float* pw_w  = (const float*)d_in[12];

    float* ws = (float*)d_ws;
    float* pooled   = ws + OFF_POOLED;
    float* denom    = ws + OFF_DENOM;
    float* cw       = ws + OFF_CW;
    float* imp      = ws + OFF_IMP;
    float* s        = ws + OFF_S;
    int*   sel      = (int*)(ws + OFF_SEL);
    int*   inv      = (int*)(ws + OFF_INV);
    float* selected = ws + OFF_SELECTED;
    float* pwT      = ws + OFF_PWT;
    float* out      = (float*)d_out;

    k_stats<<<Bz * Cz * Dz, 256, 0, stream>>>(x, pooled, denom);
    k_attn<<<Bz * Dz, 128, 0, stream>>>(pooled, ca_w1, ca_b1, ca_w2, ca_b2, cw);
    k_s<<<Bz * Dz * NCHUNK, 256, 0, stream>>>(x, denom, s);
    k_imp<<<Bz * Cz * Dz, 256, 0, stream>>>(x, s, denom, cw, alpha, imp);
    k_topk<<<Bz * Dz, 128, 0, stream>>>(imp, sel, inv);
    k_pwT<<<64, 256, 0, stream>>>(pw_w, pwT);
    k_pconv2<<<Bz * Dz * 7, 512, 0, stream>>>(x, wp, sel, selected);
    k_dw2<<<Bz * Cz * Dz, 448, 0, stream>>>(x, selected, inv, dw_w,
                                            bn_g, bn_b, bn_m, bn_v, out);
    k_pw2<<<Bz * Dz * 49, 256, 0, stream>>>(pwT, out);
}